// Round 1
// baseline (456.255 us; speedup 1.0000x reference)
//
#include <hip/hip_runtime.h>

typedef unsigned short ushort_t;
typedef unsigned int uint32;
typedef __attribute__((ext_vector_type(8))) short short8;
typedef __attribute__((ext_vector_type(4))) float f32x4;

#define HID 256
#define MI 128
// exp(s) with s = dot/T, T=0.5  ->  exp2(dot * 2/ln2)
#define INV_T_LOG2E 2.8853900817779268f
#define LN2F 0.69314718055994531f

__device__ __forceinline__ float bflo(uint32 u) { return __uint_as_float(u << 16); }
__device__ __forceinline__ float bfhi(uint32 u) { return __uint_as_float(u & 0xffff0000u); }
__device__ __forceinline__ ushort_t f2bf(float f) {
  uint32 u = __float_as_uint(f);
  u += 0x7fffu + ((u >> 16) & 1u);   // RNE
  return (ushort_t)(u >> 16);
}

// ---------------------------------------------------------------------------
// Kernel 1: p = l2norm(relu(h @ W + b)) -> bf16, for both h_v1 and h_v2.
// Block: 256 threads = 8 row-groups x 32 col-groups; 64 rows/block.
// Each thread: 8 rows x 4 cols register tile; h row staged in LDS, W via L2.
// ---------------------------------------------------------------------------
__global__ __launch_bounds__(256) void proj_norm_kernel(
    const float* __restrict__ h1, const float* __restrict__ h2,
    const float* __restrict__ W, const float* __restrict__ b,
    ushort_t* __restrict__ p1b, ushort_t* __restrict__ p2b, int n)
{
  __shared__ float sh[64 * HID];   // 64 KB
  int t = threadIdx.x;
  long R0 = (long)blockIdx.x * 64;
  const float* src = (R0 < n) ? (h1 + R0 * HID) : (h2 + (R0 - n) * HID);
  ushort_t* dst = (R0 < n) ? (p1b + R0 * MI) : (p2b + (R0 - n) * MI);

  const float4* g4 = (const float4*)src;
  float4* s4 = (float4*)sh;
  #pragma unroll
  for (int it = 0; it < 16; ++it) s4[it * 256 + t] = g4[it * 256 + t];
  __syncthreads();

  int tc = t & 31, tr = t >> 5;
  float acc[8][4];
  float4 bb = ((const float4*)b)[tc];
  #pragma unroll
  for (int rr = 0; rr < 8; ++rr) {
    acc[rr][0] = bb.x; acc[rr][1] = bb.y; acc[rr][2] = bb.z; acc[rr][3] = bb.w;
  }
  const float4* W4 = (const float4*)W;
  const float* shr = sh + tr * 8 * HID;
  for (int k = 0; k < HID; ++k) {
    float4 w = W4[k * 32 + tc];
    #pragma unroll
    for (int rr = 0; rr < 8; ++rr) {
      float hv = shr[rr * HID + k];
      acc[rr][0] += hv * w.x;
      acc[rr][1] += hv * w.y;
      acc[rr][2] += hv * w.z;
      acc[rr][3] += hv * w.w;
    }
  }
  #pragma unroll
  for (int rr = 0; rr < 8; ++rr) {
    float v0 = fmaxf(acc[rr][0], 0.f), v1 = fmaxf(acc[rr][1], 0.f);
    float v2 = fmaxf(acc[rr][2], 0.f), v3 = fmaxf(acc[rr][3], 0.f);
    float ss = v0 * v0 + v1 * v1 + v2 * v2 + v3 * v3;
    #pragma unroll
    for (int m = 1; m <= 16; m <<= 1) ss += __shfl_xor(ss, m, 64);
    float rn = rsqrtf(ss);
    ushort4 o;
    o.x = f2bf(v0 * rn); o.y = f2bf(v1 * rn); o.z = f2bf(v2 * rn); o.w = f2bf(v3 * rn);
    *(ushort4*)(dst + (tr * 8 + rr) * MI + tc * 4) = o;
  }
}

// ---------------------------------------------------------------------------
// Kernel 2: streaming sum-of-exp over the NxN similarity matrix.
// 128x128 tile/block, K=128 in one LDS phase, 16x16x32 bf16 MFMA.
// LDS XOR-swizzled (16B granule g ^ (row&15)) -> 2-way bank alias only (free).
// Epilogue: exp, cross-lane reduce, atomicAdd into rowsum/colsum.
// ---------------------------------------------------------------------------
__global__ __launch_bounds__(256) void sim_sums_kernel(
    const ushort_t* __restrict__ p1b, const ushort_t* __restrict__ p2b,
    float* __restrict__ rowsum, float* __restrict__ colsum, int n)
{
  __shared__ __align__(16) unsigned char ldsA[32768];
  __shared__ __align__(16) unsigned char ldsB[32768];
  int t = threadIdx.x;
  int lane = t & 63, wv = t >> 6;
  int wr = wv >> 1, wc = wv & 1;     // 2x2 wave grid, each wave 64x64
  int i0 = blockIdx.y * 128, j0 = blockIdx.x * 128;

  // Stage both tiles (each a contiguous 32 KB global chunk) with XOR swizzle.
  const uint4* gA = (const uint4*)(p1b + (size_t)i0 * MI);
  const uint4* gB = (const uint4*)(p2b + (size_t)j0 * MI);
  #pragma unroll
  for (int it = 0; it < 8; ++it) {
    int idx = it * 256 + t;          // 16B granule index, 2048 per tile
    int row = idx >> 4, g = idx & 15;
    int off = row * 256 + ((g ^ (row & 15)) << 4);
    *(uint4*)(ldsA + off) = gA[idx];
    *(uint4*)(ldsB + off) = gB[idx];
  }
  __syncthreads();

  f32x4 acc[4][4];
  #pragma unroll
  for (int r = 0; r < 4; ++r)
    #pragma unroll
    for (int c = 0; c < 4; ++c)
      acc[r][c] = (f32x4){0.f, 0.f, 0.f, 0.f};

  int lr = lane & 15, lg = lane >> 4;
  #pragma unroll
  for (int k = 0; k < 4; ++k) {
    short8 af[4], bfr[4];
    #pragma unroll
    for (int r = 0; r < 4; ++r) {
      int m = wr * 64 + r * 16 + lr;
      int g = k * 4 + lg;
      af[r] = *(const short8*)(ldsA + m * 256 + ((g ^ (m & 15)) << 4));
    }
    #pragma unroll
    for (int c = 0; c < 4; ++c) {
      int m = wc * 64 + c * 16 + lr;
      int g = k * 4 + lg;
      bfr[c] = *(const short8*)(ldsB + m * 256 + ((g ^ (m & 15)) << 4));
    }
    #pragma unroll
    for (int r = 0; r < 4; ++r)
      #pragma unroll
      for (int c = 0; c < 4; ++c)
        acc[r][c] = __builtin_amdgcn_mfma_f32_16x16x32_bf16(af[r], bfr[c], acc[r][c], 0, 0, 0);
  }

  // C/D layout: col = lane&15, row = (lane>>4)*4 + reg  [m89/m91 verified]
  float prs[4][4];
  float pcs[4] = {0.f, 0.f, 0.f, 0.f};
  #pragma unroll
  for (int r = 0; r < 4; ++r) { prs[r][0] = prs[r][1] = prs[r][2] = prs[r][3] = 0.f; }
  #pragma unroll
  for (int r = 0; r < 4; ++r)
    #pragma unroll
    for (int c = 0; c < 4; ++c)
      #pragma unroll
      for (int j = 0; j < 4; ++j) {
        float e = __builtin_amdgcn_exp2f(acc[r][c][j] * INV_T_LOG2E);
        prs[r][j] += e;   // partial row sum (sum over cols this lane owns)
        pcs[c] += e;      // partial col sum (sum over rows this lane owns)
      }

  // Row sums: reduce across the 16 lanes sharing lg (xor 1,2,4,8).
  #pragma unroll
  for (int r = 0; r < 4; ++r)
    #pragma unroll
    for (int j = 0; j < 4; ++j) {
      float v = prs[r][j];
      v += __shfl_xor(v, 1, 64);
      v += __shfl_xor(v, 2, 64);
      v += __shfl_xor(v, 4, 64);
      v += __shfl_xor(v, 8, 64);
      if (lr == 0) atomicAdd(&rowsum[i0 + wr * 64 + r * 16 + lg * 4 + j], v);
    }
  // Col sums: reduce across the 4 lg groups (xor 16, 32).
  #pragma unroll
  for (int c = 0; c < 4; ++c) {
    float v = pcs[c];
    v += __shfl_xor(v, 16, 64);
    v += __shfl_xor(v, 32, 64);
    if (lane < 16) atomicAdd(&colsum[j0 + wc * 64 + c * 16 + lane], v);
  }
}

// ---------------------------------------------------------------------------
// Kernel 3: per-edge positive logits, both directions.
// s1 = <p1[r], p2[c]>/T ; s2 = <p1[c], p2[r]>/T
// ---------------------------------------------------------------------------
__global__ __launch_bounds__(256) void edge_kernel(
    const int* __restrict__ pos_row, const int* __restrict__ pos_col,
    const ushort_t* __restrict__ p1b, const ushort_t* __restrict__ p2b,
    float* __restrict__ psum1, float* __restrict__ psum2,
    float* __restrict__ srow1, float* __restrict__ srow2,
    float* __restrict__ cntb, int E)
{
  int e = blockIdx.x * 256 + threadIdx.x;
  if (e >= E) return;
  int r = pos_row[e], c = pos_col[e];
  const uint4* a1 = (const uint4*)(p1b + (size_t)r * MI);
  const uint4* b1 = (const uint4*)(p2b + (size_t)c * MI);
  const uint4* a2 = (const uint4*)(p1b + (size_t)c * MI);
  const uint4* b2 = (const uint4*)(p2b + (size_t)r * MI);
  float d1 = 0.f, d2 = 0.f;
  #pragma unroll
  for (int it = 0; it < 16; ++it) {
    uint4 x = a1[it], y = b1[it];
    d1 += bflo(x.x) * bflo(y.x) + bfhi(x.x) * bfhi(y.x);
    d1 += bflo(x.y) * bflo(y.y) + bfhi(x.y) * bfhi(y.y);
    d1 += bflo(x.z) * bflo(y.z) + bfhi(x.z) * bfhi(y.z);
    d1 += bflo(x.w) * bflo(y.w) + bfhi(x.w) * bfhi(y.w);
    uint4 u = a2[it], v = b2[it];
    d2 += bflo(u.x) * bflo(v.x) + bfhi(u.x) * bfhi(v.x);
    d2 += bflo(u.y) * bflo(v.y) + bfhi(u.y) * bfhi(v.y);
    d2 += bflo(u.z) * bflo(v.z) + bfhi(u.z) * bfhi(v.z);
    d2 += bflo(u.w) * bflo(v.w) + bfhi(u.w) * bfhi(v.w);
  }
  float s1 = d1 * 2.0f, s2 = d2 * 2.0f;            // natural-log-domain logits
  float e1 = __builtin_amdgcn_exp2f(d1 * INV_T_LOG2E);
  float e2 = __builtin_amdgcn_exp2f(d2 * INV_T_LOG2E);
  atomicAdd(&psum1[r], e1);
  atomicAdd(&srow1[r], s1);
  atomicAdd(&psum2[r], e2);
  atomicAdd(&srow2[r], s2);
  atomicAdd(&cntb[r], 1.0f);
}

// ---------------------------------------------------------------------------
// Kernel 4: loss = -(1/2N) * sum_r [ srow1/cnt - log(rowsum-psum1)
//                                   + srow2/cnt - log(colsum-psum2) ]
// ---------------------------------------------------------------------------
__global__ __launch_bounds__(256) void finalize_kernel(
    const float* __restrict__ rowsum, const float* __restrict__ colsum,
    const float* __restrict__ psum1, const float* __restrict__ psum2,
    const float* __restrict__ srow1, const float* __restrict__ srow2,
    const float* __restrict__ cntb, float* __restrict__ out, int n)
{
  __shared__ float sred[4];
  float local = 0.f;
  for (int r = threadIdx.x; r < n; r += 256) {
    float inv = 1.0f / cntb[r];
    float d1 = rowsum[r] - psum1[r];
    float d2 = colsum[r] - psum2[r];
    local += srow1[r] * inv - __builtin_amdgcn_logf(d1) * LN2F;
    local += srow2[r] * inv - __builtin_amdgcn_logf(d2) * LN2F;
  }
  #pragma unroll
  for (int m = 1; m <= 32; m <<= 1) local += __shfl_xor(local, m, 64);
  int lane = threadIdx.x & 63, wv = threadIdx.x >> 6;
  if (lane == 0) sred[wv] = local;
  __syncthreads();
  if (threadIdx.x == 0) {
    float tot = sred[0] + sred[1] + sred[2] + sred[3];
    out[0] = -tot / (2.0f * n);
  }
}

extern "C" void kernel_launch(void* const* d_in, const int* in_sizes, int n_in,
                              void* d_out, int out_size, void* d_ws, size_t ws_size,
                              hipStream_t stream)
{
  const float* h1 = (const float*)d_in[0];
  const float* h2 = (const float*)d_in[1];
  const float* W  = (const float*)d_in[2];
  const float* b  = (const float*)d_in[3];
  const int* pos_row = (const int*)d_in[4];
  const int* pos_col = (const int*)d_in[5];
  int n = in_sizes[0] / HID;      // 16384
  int E = in_sizes[4];            // 65536
  float* out = (float*)d_out;

  char* ws = (char*)d_ws;
  ushort_t* p1b = (ushort_t*)ws;                       // n*128 bf16 = 4 MB
  ushort_t* p2b = p1b + (size_t)n * MI;                // 4 MB
  float* fbase  = (float*)(ws + (size_t)2 * n * MI * sizeof(ushort_t));
  float* rowsum = fbase;
  float* colsum = rowsum + n;
  float* psum1  = colsum + n;
  float* psum2  = psum1 + n;
  float* srow1  = psum2 + n;
  float* srow2  = srow1 + n;
  float* cntb   = srow2 + n;

  hipMemsetAsync(fbase, 0, (size_t)7 * n * sizeof(float), stream);
  proj_norm_kernel<<<2 * n / 64, 256, 0, stream>>>(h1, h2, W, b, p1b, p2b, n);
  dim3 g2(n / 128, n / 128);
  sim_sums_kernel<<<g2, 256, 0, stream>>>(p1b, p2b, rowsum, colsum, n);
  edge_kernel<<<(E + 255) / 256, 256, 0, stream>>>(pos_row, pos_col, p1b, p2b,
                                                   psum1, psum2, srow1, srow2, cntb, E);
  finalize_kernel<<<1, 256, 0, stream>>>(rowsum, colsum, psum1, psum2,
                                         srow1, srow2, cntb, out, n);
}

// Round 2
// 367.996 us; speedup vs baseline: 1.2398x; 1.2398x over previous
//
#include <hip/hip_runtime.h>

typedef unsigned short ushort_t;
typedef unsigned int uint32;
typedef __attribute__((ext_vector_type(8))) short short8;
typedef __attribute__((ext_vector_type(4))) float f32x4;

#define HID 256
#define MI 128
// p1 is pre-scaled by ALPHA = 2/ln2, so sim MFMA output = cos*2/ln2 and
// exp(cos/T) = exp2(acc) directly. Edge logits: s = 2*cos = d * ln2.
#define ALPHA 2.8853900817779268f
#define LN2F 0.69314718055994531f

#define AS1 __attribute__((address_space(1)))
#define AS3 __attribute__((address_space(3)))

__device__ __forceinline__ float bflo(uint32 u) { return __uint_as_float(u << 16); }
__device__ __forceinline__ float bfhi(uint32 u) { return __uint_as_float(u & 0xffff0000u); }
__device__ __forceinline__ ushort_t f2bf(float f) {
  uint32 u = __float_as_uint(f);
  u += 0x7fffu + ((u >> 16) & 1u);   // RNE
  return (ushort_t)(u >> 16);
}

// ---------------------------------------------------------------------------
// Kernel 1: p = l2norm(relu(h @ W + b)) -> bf16 (p1 additionally * ALPHA).
// ---------------------------------------------------------------------------
__global__ __launch_bounds__(256) void proj_norm_kernel(
    const float* __restrict__ h1, const float* __restrict__ h2,
    const float* __restrict__ W, const float* __restrict__ b,
    ushort_t* __restrict__ p1b, ushort_t* __restrict__ p2b, int n)
{
  __shared__ float sh[64 * HID];   // 64 KB
  int t = threadIdx.x;
  long R0 = (long)blockIdx.x * 64;
  const float* src = (R0 < n) ? (h1 + R0 * HID) : (h2 + (R0 - n) * HID);
  ushort_t* dst = (R0 < n) ? (p1b + R0 * MI) : (p2b + (R0 - n) * MI);
  float scale = (R0 < n) ? ALPHA : 1.0f;

  const float4* g4 = (const float4*)src;
  float4* s4 = (float4*)sh;
  #pragma unroll
  for (int it = 0; it < 16; ++it) s4[it * 256 + t] = g4[it * 256 + t];
  __syncthreads();

  int tc = t & 31, tr = t >> 5;
  float acc[8][4];
  float4 bb = ((const float4*)b)[tc];
  #pragma unroll
  for (int rr = 0; rr < 8; ++rr) {
    acc[rr][0] = bb.x; acc[rr][1] = bb.y; acc[rr][2] = bb.z; acc[rr][3] = bb.w;
  }
  const float4* W4 = (const float4*)W;
  const float* shr = sh + tr * 8 * HID;
  #pragma unroll 4
  for (int k = 0; k < HID; ++k) {
    float4 w = W4[k * 32 + tc];
    #pragma unroll
    for (int rr = 0; rr < 8; ++rr) {
      float hv = shr[rr * HID + k];
      acc[rr][0] += hv * w.x;
      acc[rr][1] += hv * w.y;
      acc[rr][2] += hv * w.z;
      acc[rr][3] += hv * w.w;
    }
  }
  #pragma unroll
  for (int rr = 0; rr < 8; ++rr) {
    float v0 = fmaxf(acc[rr][0], 0.f), v1 = fmaxf(acc[rr][1], 0.f);
    float v2 = fmaxf(acc[rr][2], 0.f), v3 = fmaxf(acc[rr][3], 0.f);
    float ss = v0 * v0 + v1 * v1 + v2 * v2 + v3 * v3;
    #pragma unroll
    for (int m = 1; m <= 16; m <<= 1) ss += __shfl_xor(ss, m, 64);
    float rn = rsqrtf(ss) * scale;
    ushort4 o;
    o.x = f2bf(v0 * rn); o.y = f2bf(v1 * rn); o.z = f2bf(v2 * rn); o.w = f2bf(v3 * rn);
    *(ushort4*)(dst + (tr * 8 + rr) * MI + tc * 4) = o;
  }
}

// ---------------------------------------------------------------------------
// Kernel 2: persistent strip kernel over the NxN sim matrix.
// Block owns 128 rows; sweeps a 2048-col j-chunk in 16 tiles of 128.
// A strip lives in registers for the whole sweep; B tiles staged via
// global_load_lds width=16 with XOR-swizzled gather (LDS reads 2-way = free).
// Rowsums accumulate in registers (1 atomic/row/block at the end);
// colsums accumulate in an 8KB LDS array (ds-atomics), flushed once.
// ---------------------------------------------------------------------------
__global__ __launch_bounds__(256, 4) void sim_strip_kernel(
    const ushort_t* __restrict__ p1b, const ushort_t* __restrict__ p2b,
    float* __restrict__ rowsum, float* __restrict__ colsum)
{
  __shared__ __align__(16) unsigned char ldsB[32768];
  __shared__ float ldsCol[2048];
  int t = threadIdx.x;
  int lane = t & 63, w = t >> 6;
  int lr = lane & 15, lg = lane >> 4;
  int i_base = blockIdx.y * 128;
  int jbase = blockIdx.x * 2048;

  #pragma unroll
  for (int it = 0; it < 8; ++it) ldsCol[it * 256 + t] = 0.f;

  // A fragments: this wave's 32 rows x K=128, held in registers all kernel.
  short8 afr[2][4];
  #pragma unroll
  for (int rt = 0; rt < 2; ++rt)
    #pragma unroll
    for (int kt = 0; kt < 4; ++kt) {
      int row = i_base + w * 32 + rt * 16 + lr;
      afr[rt][kt] = *(const short8*)(p1b + (size_t)row * MI + kt * 32 + lg * 8);
    }

  float rs[2][4];
  #pragma unroll
  for (int rt = 0; rt < 2; ++rt)
    #pragma unroll
    for (int r = 0; r < 4; ++r) rs[rt][r] = 0.f;

  for (int jt = 0; jt < 16; ++jt) {
    int j0 = jbase + jt * 128;
    // Stage B tile: 2048 granules of 16B; lane order matches LDS slot order,
    // global address XOR-permuted so LDS ends up swizzled.
    #pragma unroll
    for (int s = 0; s < 8; ++s) {
      int L = s * 256 + t;
      int row = L >> 4, gs = L & 15;
      const ushort_t* gp = p2b + (size_t)(j0 + row) * MI + ((gs ^ (row & 15)) << 3);
      unsigned char* lp = ldsB + s * 4096 + w * 1024;   // wave-uniform
      __builtin_amdgcn_global_load_lds((const AS1 void*)gp, (AS3 void*)lp, 16, 0, 0);
    }
    __syncthreads();

    #pragma unroll
    for (int ch = 0; ch < 2; ++ch) {
      f32x4 acc[2][4];
      #pragma unroll
      for (int rt = 0; rt < 2; ++rt)
        #pragma unroll
        for (int c4 = 0; c4 < 4; ++c4)
          acc[rt][c4] = (f32x4){0.f, 0.f, 0.f, 0.f};
      #pragma unroll
      for (int kt = 0; kt < 4; ++kt) {
        #pragma unroll
        for (int c4 = 0; c4 < 4; ++c4) {
          int nrow = (ch * 4 + c4) * 16 + lr;
          int g = kt * 4 + lg;
          short8 bf = *(const short8*)(ldsB + nrow * 256 + ((g ^ (nrow & 15)) << 4));
          acc[0][c4] = __builtin_amdgcn_mfma_f32_16x16x32_bf16(afr[0][kt], bf, acc[0][c4], 0, 0, 0);
          acc[1][c4] = __builtin_amdgcn_mfma_f32_16x16x32_bf16(afr[1][kt], bf, acc[1][c4], 0, 0, 0);
        }
      }
      // Epilogue: e = exp2(acc) (ALPHA pre-folded). D layout: col = ct*16+lr,
      // row = rt*16 + lg*4 + r.
      #pragma unroll
      for (int c4 = 0; c4 < 4; ++c4) {
        float csum = 0.f;
        #pragma unroll
        for (int rt = 0; rt < 2; ++rt)
          #pragma unroll
          for (int r = 0; r < 4; ++r) {
            float e = __builtin_amdgcn_exp2f(acc[rt][c4][r]);
            rs[rt][r] += e;
            csum += e;
          }
        atomicAdd(&ldsCol[jt * 128 + (ch * 4 + c4) * 16 + lr], csum);
      }
    }
    __syncthreads();
  }

  // Row flush: reduce over the 16 cols-lanes, one global atomic per row.
  #pragma unroll
  for (int rt = 0; rt < 2; ++rt)
    #pragma unroll
    for (int r = 0; r < 4; ++r) {
      float v = rs[rt][r];
      v += __shfl_xor(v, 1, 64);
      v += __shfl_xor(v, 2, 64);
      v += __shfl_xor(v, 4, 64);
      v += __shfl_xor(v, 8, 64);
      if (lr == 0) atomicAdd(&rowsum[i_base + w * 32 + rt * 16 + lg * 4 + r], v);
    }
  __syncthreads();
  #pragma unroll
  for (int it = 0; it < 8; ++it)
    atomicAdd(&colsum[jbase + it * 256 + t], ldsCol[it * 256 + t]);
}

// ---------------------------------------------------------------------------
// Kernel 3: per-edge positive logits, both directions.
// d = ALPHA*cos (ALPHA folded into p1b). exp term = exp2(d); ln-logit = d*ln2.
// ---------------------------------------------------------------------------
__global__ __launch_bounds__(256) void edge_kernel(
    const int* __restrict__ pos_row, const int* __restrict__ pos_col,
    const ushort_t* __restrict__ p1b, const ushort_t* __restrict__ p2b,
    float* __restrict__ psum1, float* __restrict__ psum2,
    float* __restrict__ srow1, float* __restrict__ srow2,
    float* __restrict__ cntb, int E)
{
  int e = blockIdx.x * 256 + threadIdx.x;
  if (e >= E) return;
  int r = pos_row[e], c = pos_col[e];
  const uint4* a1 = (const uint4*)(p1b + (size_t)r * MI);
  const uint4* b1 = (const uint4*)(p2b + (size_t)c * MI);
  const uint4* a2 = (const uint4*)(p1b + (size_t)c * MI);
  const uint4* b2 = (const uint4*)(p2b + (size_t)r * MI);
  float d1 = 0.f, d2 = 0.f;
  #pragma unroll
  for (int it = 0; it < 16; ++it) {
    uint4 x = a1[it], y = b1[it];
    d1 += bflo(x.x) * bflo(y.x) + bfhi(x.x) * bfhi(y.x);
    d1 += bflo(x.y) * bflo(y.y) + bfhi(x.y) * bfhi(y.y);
    d1 += bflo(x.z) * bflo(y.z) + bfhi(x.z) * bfhi(y.z);
    d1 += bflo(x.w) * bflo(y.w) + bfhi(x.w) * bfhi(y.w);
    uint4 u = a2[it], v = b2[it];
    d2 += bflo(u.x) * bflo(v.x) + bfhi(u.x) * bfhi(v.x);
    d2 += bflo(u.y) * bflo(v.y) + bfhi(u.y) * bfhi(v.y);
    d2 += bflo(u.z) * bflo(v.z) + bfhi(u.z) * bfhi(v.z);
    d2 += bflo(u.w) * bflo(v.w) + bfhi(u.w) * bfhi(v.w);
  }
  float e1 = __builtin_amdgcn_exp2f(d1);
  float e2 = __builtin_amdgcn_exp2f(d2);
  atomicAdd(&psum1[r], e1);
  atomicAdd(&srow1[r], d1 * LN2F);
  atomicAdd(&psum2[r], e2);
  atomicAdd(&srow2[r], d2 * LN2F);
  atomicAdd(&cntb[r], 1.0f);
}

// ---------------------------------------------------------------------------
// Kernel 4: loss = -(1/2N) * sum_r [ srow1/cnt - log(rowsum-psum1)
//                                   + srow2/cnt - log(colsum-psum2) ]
// ---------------------------------------------------------------------------
__global__ __launch_bounds__(256) void finalize_kernel(
    const float* __restrict__ rowsum, const float* __restrict__ colsum,
    const float* __restrict__ psum1, const float* __restrict__ psum2,
    const float* __restrict__ srow1, const float* __restrict__ srow2,
    const float* __restrict__ cntb, float* __restrict__ out, int n)
{
  __shared__ float sred[4];
  float local = 0.f;
  for (int r = threadIdx.x; r < n; r += 256) {
    float inv = 1.0f / cntb[r];
    float d1 = rowsum[r] - psum1[r];
    float d2 = colsum[r] - psum2[r];
    local += srow1[r] * inv - __builtin_amdgcn_logf(d1) * LN2F;
    local += srow2[r] * inv - __builtin_amdgcn_logf(d2) * LN2F;
  }
  #pragma unroll
  for (int m = 1; m <= 32; m <<= 1) local += __shfl_xor(local, m, 64);
  int lane = threadIdx.x & 63, wv = threadIdx.x >> 6;
  if (lane == 0) sred[wv] = local;
  __syncthreads();
  if (threadIdx.x == 0) {
    float tot = sred[0] + sred[1] + sred[2] + sred[3];
    out[0] = -tot / (2.0f * n);
  }
}

extern "C" void kernel_launch(void* const* d_in, const int* in_sizes, int n_in,
                              void* d_out, int out_size, void* d_ws, size_t ws_size,
                              hipStream_t stream)
{
  const float* h1 = (const float*)d_in[0];
  const float* h2 = (const float*)d_in[1];
  const float* W  = (const float*)d_in[2];
  const float* b  = (const float*)d_in[3];
  const int* pos_row = (const int*)d_in[4];
  const int* pos_col = (const int*)d_in[5];
  int n = in_sizes[0] / HID;      // 16384
  int E = in_sizes[4];            // 65536
  float* out = (float*)d_out;

  char* ws = (char*)d_ws;
  ushort_t* p1b = (ushort_t*)ws;                       // n*128 bf16 = 4 MB
  ushort_t* p2b = p1b + (size_t)n * MI;                // 4 MB
  float* fbase  = (float*)(ws + (size_t)2 * n * MI * sizeof(ushort_t));
  float* rowsum = fbase;
  float* colsum = rowsum + n;
  float* psum1  = colsum + n;
  float* psum2  = psum1 + n;
  float* srow1  = psum2 + n;
  float* srow2  = srow1 + n;
  float* cntb   = srow2 + n;

  hipMemsetAsync(fbase, 0, (size_t)7 * n * sizeof(float), stream);
  proj_norm_kernel<<<2 * n / 64, 256, 0, stream>>>(h1, h2, W, b, p1b, p2b, n);
  dim3 g2(n / 2048, n / 128);     // (j-chunks, i-strips) -> chunk == XCD
  sim_strip_kernel<<<g2, 256, 0, stream>>>(p1b, p2b, rowsum, colsum);
  edge_kernel<<<(E + 255) / 256, 256, 0, stream>>>(pos_row, pos_col, p1b, p2b,
                                                   psum1, psum2, srow1, srow2, cntb, E);
  finalize_kernel<<<1, 256, 0, stream>>>(rowsum, colsum, psum1, psum2,
                                         srow1, srow2, cntb, out, n);
}